// Round 1
// baseline (583.051 us; speedup 1.0000x reference)
//
#include <hip/hip_runtime.h>

// SpatiotemporalAttention: B=1, FRAMES=16, P=64, C=512, window (2,8,8)=L128,
// NH=8, HD=64, NWIN=512. All GEMMs bf16 MFMA 16x16x32, fp32 accumulate.
//
// Workspace layout (bytes):
//   [0,          67108864)  xbf  : window-ordered x, bf16 [65536][512]; reused as O after attention
//   [67108864,  134217728)  Q    : [512][8][128][64] bf16 (pre-scaled by 0.125)
//   [134217728, 201326592)  K    : [512][8][128][64] bf16
//   [201326592, 268435456)  Vt   : [512][8][64][128] bf16 (transposed)
//   [268435456, 270532608)  Wb   : Wq,Wk,Wv,Wo bf16, 512KB each
// Total: ~270.5 MB

typedef __bf16 bf16x8 __attribute__((ext_vector_type(8)));
typedef float  f32x4  __attribute__((ext_vector_type(4)));
typedef unsigned short ushort_t;

__device__ __forceinline__ unsigned short f2bf(float f) {
    unsigned int u = __float_as_uint(f);
    u += 0x7FFFu + ((u >> 16) & 1u);   // round-to-nearest-even
    return (unsigned short)(u >> 16);
}
__device__ __forceinline__ unsigned int pack2(float lo, float hi) {
    return (unsigned int)f2bf(lo) | ((unsigned int)f2bf(hi) << 16);
}

// ---------------- kernel 0: gather x into window order, fp32 -> bf16 ----------------
__global__ __launch_bounds__(256) void gather_cvt(const float* __restrict__ x,
                                                  unsigned short* __restrict__ xbf) {
    int tid = blockIdx.x * 256 + threadIdx.x;   // one thread per 8 elements
    int r = tid >> 6;                            // window-ordered row 0..65535
    int c = (tid & 63) << 3;                     // col start (8 floats)
    int w = r >> 7, l = r & 127;
    int wt = w >> 6, wy = (w >> 3) & 7, wx = w & 7;
    int lt = l >> 6, ly = (l >> 3) & 7, lx = l & 7;
    size_t n = (size_t)(wt * 2 + lt) * 4096 + (size_t)(wy * 8 + ly) * 64 + (wx * 8 + lx);
    const float4* s = (const float4*)(x + n * 512 + c);
    float4 a = s[0], b = s[1];
    uint4 o;
    o.x = pack2(a.x, a.y); o.y = pack2(a.z, a.w);
    o.z = pack2(b.x, b.y); o.w = pack2(b.z, b.w);
    *(uint4*)(xbf + (size_t)r * 512 + c) = o;
}

// ---------------- kernel 1: weight fp32 -> bf16 ----------------
__global__ __launch_bounds__(256) void cvt_w(const float* __restrict__ s,
                                             unsigned short* __restrict__ d) {
    int tid = blockIdx.x * 256 + threadIdx.x;   // per 8 elements
    const float4* sp = (const float4*)s + (size_t)tid * 2;
    float4 a = sp[0], b = sp[1];
    uint4 o;
    o.x = pack2(a.x, a.y); o.y = pack2(a.z, a.w);
    o.z = pack2(b.x, b.y); o.w = pack2(b.z, b.w);
    ((uint4*)d)[tid] = o;
}

// ---------------- kernel 2: QKV projection GEMM ----------------
// grid (4 ncol-blocks, 512 windows, 3 projections), 256 threads (4 waves, 2x2)
__global__ __launch_bounds__(256) void qkv_gemm(const unsigned short* __restrict__ xbf,
                                                const unsigned short* __restrict__ wb,
                                                unsigned short* __restrict__ Qb,
                                                unsigned short* __restrict__ Kb,
                                                unsigned short* __restrict__ Vb) {
    int nb = blockIdx.x, w = blockIdx.y, pj = blockIdx.z;
    const unsigned short* A = xbf + (size_t)w * 128 * 512;
    const unsigned short* B = wb + (size_t)pj * 262144 + (size_t)nb * 128 * 512;
    __shared__ unsigned short sA[128 * 72];
    __shared__ unsigned short sB[128 * 72];
    f32x4 acc[4][4] = {};
    int t = threadIdx.x, lane = t & 63, wv = t >> 6;
    int wm = wv & 1, wn = wv >> 1, quad = lane >> 4, lc = lane & 15;

    for (int k0 = 0; k0 < 512; k0 += 64) {
        __syncthreads();
        #pragma unroll
        for (int i = 0; i < 4; i++) {
            int idx = t + i * 256;           // 0..1023 chunks of 8
            int r = idx >> 3, c = idx & 7;
            *(uint4*)(&sA[r * 72 + c * 8]) = *(const uint4*)(A + (size_t)r * 512 + k0 + c * 8);
            *(uint4*)(&sB[r * 72 + c * 8]) = *(const uint4*)(B + (size_t)r * 512 + k0 + c * 8);
        }
        __syncthreads();
        #pragma unroll
        for (int ks = 0; ks < 2; ks++) {
            bf16x8 af[4], bfr[4];
            #pragma unroll
            for (int i = 0; i < 4; i++) {
                af[i]  = *(const bf16x8*)(&sA[(wm * 64 + i * 16 + lc) * 72 + quad * 8 + ks * 32]);
                bfr[i] = *(const bf16x8*)(&sB[(wn * 64 + i * 16 + lc) * 72 + quad * 8 + ks * 32]);
            }
            #pragma unroll
            for (int mi = 0; mi < 4; mi++)
                #pragma unroll
                for (int ni = 0; ni < 4; ni++)
                    acc[mi][ni] = __builtin_amdgcn_mfma_f32_16x16x32_bf16(af[mi], bfr[ni], acc[mi][ni], 0, 0, 0);
        }
    }

    int c0 = nb * 128 + wn * 64;
    #pragma unroll
    for (int mi = 0; mi < 4; mi++)
        #pragma unroll
        for (int ni = 0; ni < 4; ni++)
            #pragma unroll
            for (int rg = 0; rg < 4; rg++) {
                int col = c0 + ni * 16 + lc;
                int h = col >> 6, d = col & 63;
                int l = wm * 64 + mi * 16 + quad * 4 + rg;
                float v = acc[mi][ni][rg];
                if (pj == 0)
                    Qb[(((size_t)w * 8 + h) * 128 + l) * 64 + d] = f2bf(v * 0.125f);
                else if (pj == 1)
                    Kb[(((size_t)w * 8 + h) * 128 + l) * 64 + d] = f2bf(v);
                else
                    Vb[(((size_t)w * 8 + h) * 64 + d) * 128 + l] = f2bf(v);
            }
}

// ---------------- kernel 3: per-(window,head) attention ----------------
// grid (8 heads, 512 windows), 256 threads (4 waves); wave wv owns rows 32wv..32wv+31
__global__ __launch_bounds__(256) void attn(const unsigned short* __restrict__ Qb,
                                            const unsigned short* __restrict__ Kb,
                                            const unsigned short* __restrict__ Vb,
                                            unsigned short* __restrict__ O) {
    int h = blockIdx.x, w = blockIdx.y;
    size_t base = ((size_t)w * 8 + h) * 8192;
    const unsigned short* q = Qb + base;
    const unsigned short* k = Kb + base;
    const unsigned short* v = Vb + base;   // Vt [64][128]

    __shared__ unsigned short smem[27136];           // 54272 bytes
    unsigned short* sV = smem;                       // [64][136]  (17408 B)
    unsigned short* sQ = smem + 8704;                // [128][72]  (18432 B)
    unsigned short* sK = smem + 8704 + 9216;         // [128][72]  (18432 B)
    unsigned short* sP = smem + 8704;                // [128][136] overlays Q∪K (34816 B)

    int t = threadIdx.x, lane = t & 63, wv = t >> 6;
    int quad = lane >> 4, lc = lane & 15;

    #pragma unroll
    for (int i = 0; i < 4; i++) {
        int idx = t + i * 256;
        int r = idx >> 3, c = idx & 7;               // Q/K: 128 rows x 8 chunks
        *(uint4*)(&sQ[r * 72 + c * 8]) = *(const uint4*)(q + (size_t)r * 64 + c * 8);
        *(uint4*)(&sK[r * 72 + c * 8]) = *(const uint4*)(k + (size_t)r * 64 + c * 8);
        int rv = idx >> 4, cv = idx & 15;            // Vt: 64 rows x 16 chunks
        *(uint4*)(&sV[rv * 136 + cv * 8]) = *(const uint4*)(v + (size_t)rv * 128 + cv * 8);
    }
    __syncthreads();

    // S = Q @ K^T  (Q pre-scaled by 1/8)
    f32x4 acc[2][8] = {};
    #pragma unroll
    for (int ks = 0; ks < 2; ks++) {
        bf16x8 af[2];
        #pragma unroll
        for (int mi = 0; mi < 2; mi++)
            af[mi] = *(const bf16x8*)(&sQ[(wv * 32 + mi * 16 + lc) * 72 + quad * 8 + ks * 32]);
        #pragma unroll
        for (int ni = 0; ni < 8; ni++) {
            bf16x8 bfr = *(const bf16x8*)(&sK[(ni * 16 + lc) * 72 + quad * 8 + ks * 32]);
            #pragma unroll
            for (int mi = 0; mi < 2; mi++)
                acc[mi][ni] = __builtin_amdgcn_mfma_f32_16x16x32_bf16(af[mi], bfr, acc[mi][ni], 0, 0, 0);
        }
    }

    // softmax fully in registers: row (mi,rg) lives in one 16-lane quad group
    #pragma unroll
    for (int mi = 0; mi < 2; mi++)
        #pragma unroll
        for (int rg = 0; rg < 4; rg++) {
            float m = -1e30f;
            #pragma unroll
            for (int ni = 0; ni < 8; ni++) m = fmaxf(m, acc[mi][ni][rg]);
            #pragma unroll
            for (int off = 1; off < 16; off <<= 1) m = fmaxf(m, __shfl_xor(m, off, 64));
            float s = 0.f;
            #pragma unroll
            for (int ni = 0; ni < 8; ni++) {
                float e = __expf(acc[mi][ni][rg] - m);
                acc[mi][ni][rg] = e;
                s += e;
            }
            #pragma unroll
            for (int off = 1; off < 16; off <<= 1) s += __shfl_xor(s, off, 64);
            float inv = 1.0f / s;
            #pragma unroll
            for (int ni = 0; ni < 8; ni++) acc[mi][ni][rg] *= inv;
        }

    __syncthreads();   // all waves done reading sQ/sK before P overlays them
    #pragma unroll
    for (int mi = 0; mi < 2; mi++)
        #pragma unroll
        for (int ni = 0; ni < 8; ni++)
            #pragma unroll
            for (int rg = 0; rg < 4; rg++) {
                int r = wv * 32 + mi * 16 + quad * 4 + rg;
                int c = ni * 16 + lc;
                sP[r * 136 + c] = f2bf(acc[mi][ni][rg]);
            }
    __syncthreads();

    // O = P @ V   (Vt as [d][k] NT operand)
    f32x4 oc[2][4] = {};
    #pragma unroll
    for (int ks = 0; ks < 4; ks++) {
        bf16x8 af[2];
        #pragma unroll
        for (int mi = 0; mi < 2; mi++)
            af[mi] = *(const bf16x8*)(&sP[(wv * 32 + mi * 16 + lc) * 136 + quad * 8 + ks * 32]);
        #pragma unroll
        for (int ni = 0; ni < 4; ni++) {
            bf16x8 bfr = *(const bf16x8*)(&sV[(ni * 16 + lc) * 136 + quad * 8 + ks * 32]);
            #pragma unroll
            for (int mi = 0; mi < 2; mi++)
                oc[mi][ni] = __builtin_amdgcn_mfma_f32_16x16x32_bf16(af[mi], bfr, oc[mi][ni], 0, 0, 0);
        }
    }

    #pragma unroll
    for (int mi = 0; mi < 2; mi++)
        #pragma unroll
        for (int ni = 0; ni < 4; ni++)
            #pragma unroll
            for (int rg = 0; rg < 4; rg++) {
                int l = wv * 32 + mi * 16 + quad * 4 + rg;
                int d = ni * 16 + lc;
                O[((size_t)w * 128 + l) * 512 + h * 64 + d] = f2bf(oc[mi][ni][rg]);
            }
}

// ---------------- kernel 4: output projection + bias + window merge ----------------
__global__ __launch_bounds__(256) void oproj_gemm(const unsigned short* __restrict__ A,
                                                  const unsigned short* __restrict__ Bw,
                                                  const float* __restrict__ bo,
                                                  float* __restrict__ out) {
    int nb = blockIdx.x, rb = blockIdx.y;
    const unsigned short* Ab = A + (size_t)rb * 128 * 512;
    const unsigned short* Bb = Bw + (size_t)nb * 128 * 512;
    __shared__ unsigned short sA[128 * 72];
    __shared__ unsigned short sB[128 * 72];
    f32x4 acc[4][4] = {};
    int t = threadIdx.x, lane = t & 63, wv = t >> 6;
    int wm = wv & 1, wn = wv >> 1, quad = lane >> 4, lc = lane & 15;

    for (int k0 = 0; k0 < 512; k0 += 64) {
        __syncthreads();
        #pragma unroll
        for (int i = 0; i < 4; i++) {
            int idx = t + i * 256;
            int r = idx >> 3, c = idx & 7;
            *(uint4*)(&sA[r * 72 + c * 8]) = *(const uint4*)(Ab + (size_t)r * 512 + k0 + c * 8);
            *(uint4*)(&sB[r * 72 + c * 8]) = *(const uint4*)(Bb + (size_t)r * 512 + k0 + c * 8);
        }
        __syncthreads();
        #pragma unroll
        for (int ks = 0; ks < 2; ks++) {
            bf16x8 af[4], bfr[4];
            #pragma unroll
            for (int i = 0; i < 4; i++) {
                af[i]  = *(const bf16x8*)(&sA[(wm * 64 + i * 16 + lc) * 72 + quad * 8 + ks * 32]);
                bfr[i] = *(const bf16x8*)(&sB[(wn * 64 + i * 16 + lc) * 72 + quad * 8 + ks * 32]);
            }
            #pragma unroll
            for (int mi = 0; mi < 4; mi++)
                #pragma unroll
                for (int ni = 0; ni < 4; ni++)
                    acc[mi][ni] = __builtin_amdgcn_mfma_f32_16x16x32_bf16(af[mi], bfr[ni], acc[mi][ni], 0, 0, 0);
        }
    }

    #pragma unroll
    for (int mi = 0; mi < 4; mi++)
        #pragma unroll
        for (int rg = 0; rg < 4; rg++) {
            int r = rb * 128 + wm * 64 + mi * 16 + quad * 4 + rg;
            int w = r >> 7, l = r & 127;
            int wt = w >> 6, wy = (w >> 3) & 7, wx = w & 7;
            int lt = l >> 6, ly = (l >> 3) & 7, lx = l & 7;
            size_t n = (size_t)(wt * 2 + lt) * 4096 + (size_t)(wy * 8 + ly) * 64 + (wx * 8 + lx);
            #pragma unroll
            for (int ni = 0; ni < 4; ni++) {
                int col = nb * 128 + wn * 64 + ni * 16 + lc;
                out[n * 512 + col] = acc[mi][ni][rg] + bo[col];
            }
        }
}

extern "C" void kernel_launch(void* const* d_in, const int* in_sizes, int n_in,
                              void* d_out, int out_size, void* d_ws, size_t ws_size,
                              hipStream_t stream) {
    const float* x  = (const float*)d_in[0];
    const float* Wq = (const float*)d_in[1];
    const float* Wk = (const float*)d_in[2];
    const float* Wv = (const float*)d_in[3];
    const float* Wo = (const float*)d_in[4];
    const float* bo = (const float*)d_in[5];
    float* out = (float*)d_out;

    char* ws = (char*)d_ws;
    unsigned short* xbf = (unsigned short*)(ws);                  // also O after attention
    unsigned short* Qb  = (unsigned short*)(ws + 67108864);
    unsigned short* Kb  = (unsigned short*)(ws + 134217728);
    unsigned short* Vb  = (unsigned short*)(ws + 201326592);
    unsigned short* Wqb = (unsigned short*)(ws + 268435456);      // Wq,Wk,Wv,Wo consecutive

    gather_cvt<<<16384, 256, 0, stream>>>(x, xbf);
    cvt_w<<<128, 256, 0, stream>>>(Wq, Wqb);
    cvt_w<<<128, 256, 0, stream>>>(Wk, Wqb + 262144);
    cvt_w<<<128, 256, 0, stream>>>(Wv, Wqb + 524288);
    cvt_w<<<128, 256, 0, stream>>>(Wo, Wqb + 786432);

    qkv_gemm<<<dim3(4, 512, 3), 256, 0, stream>>>(xbf, Wqb, Qb, Kb, Vb);
    attn<<<dim3(8, 512), 256, 0, stream>>>(Qb, Kb, Vb, xbf);
    oproj_gemm<<<dim3(4, 512), 256, 0, stream>>>(xbf, Wqb + 786432, bo, out);
}

// Round 2
// 536.924 us; speedup vs baseline: 1.0859x; 1.0859x over previous
//
#include <hip/hip_runtime.h>

// SpatiotemporalAttention: B=1, FRAMES=16, P=64, C=512, window (2,8,8)=L128,
// NH=8, HD=64, NWIN=512. All GEMMs bf16 MFMA 16x16x32, fp32 accumulate.
//
// R1: global_load_lds width=16 staging everywhere (m93->m97 technique),
//     XOR-swizzled LDS (chunk ^= row&7) instead of +pad (glds forbids padding),
//     attn LDS 54->48KB (3 blocks/CU), cvt_w merged to one launch.
//
// Workspace layout (bytes):
//   [0,          67108864)  xbf  : window-ordered x, bf16 [65536][512]; reused as O after attention
//   [67108864,  134217728)  Q    : [512][8][128][64] bf16 (pre-scaled by 0.125)
//   [134217728, 201326592)  K    : [512][8][128][64] bf16
//   [201326592, 268435456)  Vt   : [512][8][64][128] bf16 (transposed)
//   [268435456, 270532608)  Wb   : Wq,Wk,Wv,Wo bf16, 512KB each

typedef __bf16 bf16x8 __attribute__((ext_vector_type(8)));
typedef float  f32x4  __attribute__((ext_vector_type(4)));

__device__ __forceinline__ unsigned short f2bf(float f) {
    unsigned int u = __float_as_uint(f);
    u += 0x7FFFu + ((u >> 16) & 1u);   // round-to-nearest-even
    return (unsigned short)(u >> 16);
}
__device__ __forceinline__ unsigned int pack2(float lo, float hi) {
    return (unsigned int)f2bf(lo) | ((unsigned int)f2bf(hi) << 16);
}
__device__ __forceinline__ void glds16(const void* g, void* l) {
    __builtin_amdgcn_global_load_lds(
        (const __attribute__((address_space(1))) unsigned int*)g,
        (__attribute__((address_space(3))) unsigned int*)l, 16, 0, 0);
}

// ---------------- kernel 0: gather x into window order, fp32 -> bf16 ----------------
__global__ __launch_bounds__(256) void gather_cvt(const float* __restrict__ x,
                                                  unsigned short* __restrict__ xbf) {
    int tid = blockIdx.x * 256 + threadIdx.x;   // one thread per 8 elements
    int r = tid >> 6;                            // window-ordered row 0..65535
    int c = (tid & 63) << 3;                     // col start (8 floats)
    int w = r >> 7, l = r & 127;
    int wt = w >> 6, wy = (w >> 3) & 7, wx = w & 7;
    int lt = l >> 6, ly = (l >> 3) & 7, lx = l & 7;
    size_t n = (size_t)(wt * 2 + lt) * 4096 + (size_t)(wy * 8 + ly) * 64 + (wx * 8 + lx);
    const float4* s = (const float4*)(x + n * 512 + c);
    float4 a = s[0], b = s[1];
    uint4 o;
    o.x = pack2(a.x, a.y); o.y = pack2(a.z, a.w);
    o.z = pack2(b.x, b.y); o.w = pack2(b.z, b.w);
    *(uint4*)(xbf + (size_t)r * 512 + c) = o;
}

// ---------------- kernel 1: weights fp32 -> bf16, all 4 in one launch ----------------
__global__ __launch_bounds__(256) void cvt_w4(const float* __restrict__ Wq,
                                              const float* __restrict__ Wk,
                                              const float* __restrict__ Wv,
                                              const float* __restrict__ Wo,
                                              unsigned short* __restrict__ d) {
    int b = blockIdx.x >> 7;                     // which weight
    int tid = (blockIdx.x & 127) * 256 + threadIdx.x;   // per 8 elements
    const float* s = (b == 0) ? Wq : (b == 1) ? Wk : (b == 2) ? Wv : Wo;
    const float4* sp = (const float4*)s + (size_t)tid * 2;
    float4 a = sp[0], bb = sp[1];
    uint4 o;
    o.x = pack2(a.x, a.y); o.y = pack2(a.z, a.w);
    o.z = pack2(bb.x, bb.y); o.w = pack2(bb.z, bb.w);
    ((uint4*)(d + (size_t)b * 262144))[tid] = o;
}

// ---------------- kernel 2: QKV projection GEMM ----------------
// grid (4 ncol-blocks, 512 windows, 3 projections), 256 threads (4 waves, 2x2)
// LDS tiles [128][64] bf16, XOR-swizzled: chunk-of-16B stored at (c ^ (row&7)).
__global__ __launch_bounds__(256) void qkv_gemm(const unsigned short* __restrict__ xbf,
                                                const unsigned short* __restrict__ wb,
                                                unsigned short* __restrict__ Qb,
                                                unsigned short* __restrict__ Kb,
                                                unsigned short* __restrict__ Vb) {
    int nb = blockIdx.x, w = blockIdx.y, pj = blockIdx.z;
    const unsigned short* A = xbf + (size_t)w * 128 * 512;
    const unsigned short* B = wb + (size_t)pj * 262144 + (size_t)nb * 128 * 512;
    __shared__ unsigned short sA[128 * 64];
    __shared__ unsigned short sB[128 * 64];
    f32x4 acc[4][4] = {};
    int t = threadIdx.x, lane = t & 63, wv = t >> 6;
    int wm = wv & 1, wn = wv >> 1, quad = lane >> 4, lc = lane & 15;
    int sw = lc & 7;

    // staging geometry: slot s = t + i*256; r = (t>>3) + i*32; sc = t&7.
    // (r&7) is i-independent, so the swizzled source chunk is constant.
    int sr = t >> 3;
    int gco = ((t & 7) ^ (sr & 7)) * 8;          // global col offset (elements)

    for (int k0 = 0; k0 < 512; k0 += 64) {
        __syncthreads();
        #pragma unroll
        for (int i = 0; i < 4; i++) {
            int r = sr + i * 32;
            glds16(A + (size_t)r * 512 + k0 + gco, sA + (t + i * 256) * 8);
            glds16(B + (size_t)r * 512 + k0 + gco, sB + (t + i * 256) * 8);
        }
        __syncthreads();
        #pragma unroll
        for (int ks = 0; ks < 2; ks++) {
            int ch = ((quad + ks * 4) ^ sw) * 8;
            bf16x8 af[4], bfr[4];
            #pragma unroll
            for (int i = 0; i < 4; i++) {
                af[i]  = *(const bf16x8*)(&sA[(wm * 64 + i * 16 + lc) * 64 + ch]);
                bfr[i] = *(const bf16x8*)(&sB[(wn * 64 + i * 16 + lc) * 64 + ch]);
            }
            #pragma unroll
            for (int mi = 0; mi < 4; mi++)
                #pragma unroll
                for (int ni = 0; ni < 4; ni++)
                    acc[mi][ni] = __builtin_amdgcn_mfma_f32_16x16x32_bf16(af[mi], bfr[ni], acc[mi][ni], 0, 0, 0);
        }
    }

    int c0 = nb * 128 + wn * 64;
    #pragma unroll
    for (int mi = 0; mi < 4; mi++)
        #pragma unroll
        for (int ni = 0; ni < 4; ni++)
            #pragma unroll
            for (int rg = 0; rg < 4; rg++) {
                int col = c0 + ni * 16 + lc;
                int h = col >> 6, d = col & 63;
                int l = wm * 64 + mi * 16 + quad * 4 + rg;
                float v = acc[mi][ni][rg];
                if (pj == 0)
                    Qb[(((size_t)w * 8 + h) * 128 + l) * 64 + d] = f2bf(v * 0.125f);
                else if (pj == 1)
                    Kb[(((size_t)w * 8 + h) * 128 + l) * 64 + d] = f2bf(v);
                else
                    Vb[(((size_t)w * 8 + h) * 64 + d) * 128 + l] = f2bf(v);
            }
}

// ---------------- kernel 3: per-(window,head) attention ----------------
// grid (8 heads, 512 windows), 256 threads (4 waves); wave wv owns rows 32wv..32wv+31
// LDS 48KB: sV [64][128], sQ [128][64], sK [128][64]; sP [128][128] overlays sQ+sK.
// All tiles XOR-swizzled (16B chunk position ^= row&7).
__global__ __launch_bounds__(256) void attn(const unsigned short* __restrict__ Qb,
                                            const unsigned short* __restrict__ Kb,
                                            const unsigned short* __restrict__ Vb,
                                            unsigned short* __restrict__ O) {
    int h = blockIdx.x, w = blockIdx.y;
    size_t base = ((size_t)w * 8 + h) * 8192;
    const unsigned short* q = Qb + base;
    const unsigned short* k = Kb + base;
    const unsigned short* v = Vb + base;   // Vt [64][128]

    __shared__ unsigned short smem[24576];           // 49152 bytes
    unsigned short* sV = smem;                       // [64][128] swizzled
    unsigned short* sQ = smem + 8192;                // [128][64] swizzled
    unsigned short* sK = smem + 16384;               // [128][64] swizzled
    unsigned short* sP = smem + 8192;                // [128][128] overlays Q+K exactly

    int t = threadIdx.x, lane = t & 63, wv = t >> 6;
    int quad = lane >> 4, lc = lane & 15;
    int sw = lc & 7;

    #pragma unroll
    for (int i = 0; i < 4; i++) {
        int s = t + i * 256;
        int r = s >> 3;
        int cq = ((s & 7) ^ (r & 7)) * 8;            // Q/K: 8 chunks/row
        glds16(q + (size_t)r * 64 + cq, sQ + s * 8);
        glds16(k + (size_t)r * 64 + cq, sK + s * 8);
        int rv = s >> 4;
        int cv = (((s & 15) ^ (rv & 7))) * 8;        // V: 16 chunks/row, swizzle low 3 bits
        glds16(v + (size_t)rv * 128 + cv, sV + s * 8);
    }
    __syncthreads();

    // S = Q @ K^T  (Q pre-scaled by 1/8)
    f32x4 acc[2][8] = {};
    #pragma unroll
    for (int ks = 0; ks < 2; ks++) {
        int ch = ((quad + ks * 4) ^ sw) * 8;
        bf16x8 af[2];
        #pragma unroll
        for (int mi = 0; mi < 2; mi++)
            af[mi] = *(const bf16x8*)(&sQ[(wv * 32 + mi * 16 + lc) * 64 + ch]);
        #pragma unroll
        for (int ni = 0; ni < 8; ni++) {
            bf16x8 bfr = *(const bf16x8*)(&sK[(ni * 16 + lc) * 64 + ch]);
            #pragma unroll
            for (int mi = 0; mi < 2; mi++)
                acc[mi][ni] = __builtin_amdgcn_mfma_f32_16x16x32_bf16(af[mi], bfr, acc[mi][ni], 0, 0, 0);
        }
    }

    // softmax fully in registers: row (mi,rg) lives in one 16-lane quad group
    #pragma unroll
    for (int mi = 0; mi < 2; mi++)
        #pragma unroll
        for (int rg = 0; rg < 4; rg++) {
            float m = -1e30f;
            #pragma unroll
            for (int ni = 0; ni < 8; ni++) m = fmaxf(m, acc[mi][ni][rg]);
            #pragma unroll
            for (int off = 1; off < 16; off <<= 1) m = fmaxf(m, __shfl_xor(m, off, 64));
            float s = 0.f;
            #pragma unroll
            for (int ni = 0; ni < 8; ni++) {
                float e = __expf(acc[mi][ni][rg] - m);
                acc[mi][ni][rg] = e;
                s += e;
            }
            #pragma unroll
            for (int off = 1; off < 16; off <<= 1) s += __shfl_xor(s, off, 64);
            float inv = 1.0f / s;
            #pragma unroll
            for (int ni = 0; ni < 8; ni++) acc[mi][ni][rg] *= inv;
        }

    __syncthreads();   // all waves done reading sQ/sK before P overlays them
    #pragma unroll
    for (int mi = 0; mi < 2; mi++)
        #pragma unroll
        for (int ni = 0; ni < 8; ni++)
            #pragma unroll
            for (int rg = 0; rg < 4; rg++) {
                int r = wv * 32 + mi * 16 + quad * 4 + rg;
                int c = ni * 16 + lc;
                sP[r * 128 + (((c >> 3) ^ (r & 7)) << 3) + (c & 7)] = f2bf(acc[mi][ni][rg]);
            }
    __syncthreads();

    // O = P @ V   (Vt as [d][k] NT operand)
    f32x4 oc[2][4] = {};
    #pragma unroll
    for (int ks = 0; ks < 4; ks++) {
        int ch = ((quad + ks * 4) ^ sw) * 8;         // 16 chunks, swizzle low 3 bits
        bf16x8 af[2];
        #pragma unroll
        for (int mi = 0; mi < 2; mi++)
            af[mi] = *(const bf16x8*)(&sP[(wv * 32 + mi * 16 + lc) * 128 + ch]);
        #pragma unroll
        for (int ni = 0; ni < 4; ni++) {
            bf16x8 bfr = *(const bf16x8*)(&sV[(ni * 16 + lc) * 128 + ch]);
            #pragma unroll
            for (int mi = 0; mi < 2; mi++)
                oc[mi][ni] = __builtin_amdgcn_mfma_f32_16x16x32_bf16(af[mi], bfr, oc[mi][ni], 0, 0, 0);
        }
    }

    #pragma unroll
    for (int mi = 0; mi < 2; mi++)
        #pragma unroll
        for (int ni = 0; ni < 4; ni++)
            #pragma unroll
            for (int rg = 0; rg < 4; rg++) {
                int l = wv * 32 + mi * 16 + quad * 4 + rg;
                int d = ni * 16 + lc;
                O[((size_t)w * 128 + l) * 512 + h * 64 + d] = f2bf(oc[mi][ni][rg]);
            }
}

// ---------------- kernel 4: output projection + bias + window merge ----------------
__global__ __launch_bounds__(256) void oproj_gemm(const unsigned short* __restrict__ A,
                                                  const unsigned short* __restrict__ Bw,
                                                  const float* __restrict__ bo,
                                                  float* __restrict__ out) {
    int nb = blockIdx.x, rb = blockIdx.y;
    const unsigned short* Ab = A + (size_t)rb * 128 * 512;
    const unsigned short* Bb = Bw + (size_t)nb * 128 * 512;
    __shared__ unsigned short sA[128 * 64];
    __shared__ unsigned short sB[128 * 64];
    f32x4 acc[4][4] = {};
    int t = threadIdx.x, lane = t & 63, wv = t >> 6;
    int wm = wv & 1, wn = wv >> 1, quad = lane >> 4, lc = lane & 15;
    int sw = lc & 7;

    int sr = t >> 3;
    int gco = ((t & 7) ^ (sr & 7)) * 8;

    for (int k0 = 0; k0 < 512; k0 += 64) {
        __syncthreads();
        #pragma unroll
        for (int i = 0; i < 4; i++) {
            int r = sr + i * 32;
            glds16(Ab + (size_t)r * 512 + k0 + gco, sA + (t + i * 256) * 8);
            glds16(Bb + (size_t)r * 512 + k0 + gco, sB + (t + i * 256) * 8);
        }
        __syncthreads();
        #pragma unroll
        for (int ks = 0; ks < 2; ks++) {
            int ch = ((quad + ks * 4) ^ sw) * 8;
            bf16x8 af[4], bfr[4];
            #pragma unroll
            for (int i = 0; i < 4; i++) {
                af[i]  = *(const bf16x8*)(&sA[(wm * 64 + i * 16 + lc) * 64 + ch]);
                bfr[i] = *(const bf16x8*)(&sB[(wn * 64 + i * 16 + lc) * 64 + ch]);
            }
            #pragma unroll
            for (int mi = 0; mi < 4; mi++)
                #pragma unroll
                for (int ni = 0; ni < 4; ni++)
                    acc[mi][ni] = __builtin_amdgcn_mfma_f32_16x16x32_bf16(af[mi], bfr[ni], acc[mi][ni], 0, 0, 0);
        }
    }

    float bias[4];
    #pragma unroll
    for (int ni = 0; ni < 4; ni++)
        bias[ni] = bo[nb * 128 + wn * 64 + ni * 16 + lc];

    #pragma unroll
    for (int mi = 0; mi < 4; mi++)
        #pragma unroll
        for (int rg = 0; rg < 4; rg++) {
            int r = rb * 128 + wm * 64 + mi * 16 + quad * 4 + rg;
            int w = r >> 7, l = r & 127;
            int wt = w >> 6, wy = (w >> 3) & 7, wx = w & 7;
            int lt = l >> 6, ly = (l >> 3) & 7, lx = l & 7;
            size_t n = (size_t)(wt * 2 + lt) * 4096 + (size_t)(wy * 8 + ly) * 64 + (wx * 8 + lx);
            #pragma unroll
            for (int ni = 0; ni < 4; ni++) {
                int col = nb * 128 + wn * 64 + ni * 16 + lc;
                out[n * 512 + col] = acc[mi][ni][rg] + bias[ni];
            }
        }
}

extern "C" void kernel_launch(void* const* d_in, const int* in_sizes, int n_in,
                              void* d_out, int out_size, void* d_ws, size_t ws_size,
                              hipStream_t stream) {
    const float* x  = (const float*)d_in[0];
    const float* Wq = (const float*)d_in[1];
    const float* Wk = (const float*)d_in[2];
    const float* Wv = (const float*)d_in[3];
    const float* Wo = (const float*)d_in[4];
    const float* bo = (const float*)d_in[5];
    float* out = (float*)d_out;

    char* ws = (char*)d_ws;
    unsigned short* xbf = (unsigned short*)(ws);                  // also O after attention
    unsigned short* Qb  = (unsigned short*)(ws + 67108864);
    unsigned short* Kb  = (unsigned short*)(ws + 134217728);
    unsigned short* Vb  = (unsigned short*)(ws + 201326592);
    unsigned short* Wqb = (unsigned short*)(ws + 268435456);      // Wq,Wk,Wv,Wo consecutive

    gather_cvt<<<16384, 256, 0, stream>>>(x, xbf);
    cvt_w4<<<512, 256, 0, stream>>>(Wq, Wk, Wv, Wo, Wqb);

    qkv_gemm<<<dim3(4, 512, 3), 256, 0, stream>>>(xbf, Wqb, Qb, Kb, Vb);
    attn<<<dim3(8, 512), 256, 0, stream>>>(Qb, Kb, Vb, xbf);
    oproj_gemm<<<dim3(4, 512), 256, 0, stream>>>(xbf, Wqb + 786432, bo, out);
}

// Round 3
// 482.123 us; speedup vs baseline: 1.2093x; 1.1137x over previous
//
#include <hip/hip_runtime.h>

// SpatiotemporalAttention: B=1, FRAMES=16, P=64, C=512, window (2,8,8)=L128,
// NH=8, HD=64, NWIN=512. All GEMMs bf16 MFMA 16x16x32, fp32 accumulate.
//
// R2: qkv_gemm fuses the 3 projections into one block (A staged once per
//     k-iter, 96 MFMA/barrier instead of 32, 3x less A traffic), XCD-aware
//     flat-grid decode co-locates A-panel sharers on one XCD L2 (qkv+oproj).
//
// Workspace layout (bytes):
//   [0,          67108864)  xbf  : window-ordered x, bf16 [65536][512]; reused as O after attention
//   [67108864,  134217728)  Q    : [512][8][128][64] bf16 (pre-scaled by 0.125)
//   [134217728, 201326592)  K    : [512][8][128][64] bf16
//   [201326592, 268435456)  Vt   : [512][8][64][128] bf16 (transposed)
//   [268435456, 270532608)  Wb   : Wq,Wk,Wv,Wo bf16, 512KB each

typedef __bf16 bf16x8 __attribute__((ext_vector_type(8)));
typedef float  f32x4  __attribute__((ext_vector_type(4)));

__device__ __forceinline__ unsigned short f2bf(float f) {
    unsigned int u = __float_as_uint(f);
    u += 0x7FFFu + ((u >> 16) & 1u);   // round-to-nearest-even
    return (unsigned short)(u >> 16);
}
__device__ __forceinline__ unsigned int pack2(float lo, float hi) {
    return (unsigned int)f2bf(lo) | ((unsigned int)f2bf(hi) << 16);
}
__device__ __forceinline__ void glds16(const void* g, void* l) {
    __builtin_amdgcn_global_load_lds(
        (const __attribute__((address_space(1))) unsigned int*)g,
        (__attribute__((address_space(3))) unsigned int*)l, 16, 0, 0);
}

// ---------------- kernel 0: gather x into window order, fp32 -> bf16 ----------------
__global__ __launch_bounds__(256) void gather_cvt(const float* __restrict__ x,
                                                  unsigned short* __restrict__ xbf) {
    int tid = blockIdx.x * 256 + threadIdx.x;   // one thread per 8 elements
    int r = tid >> 6;                            // window-ordered row 0..65535
    int c = (tid & 63) << 3;                     // col start (8 floats)
    int w = r >> 7, l = r & 127;
    int wt = w >> 6, wy = (w >> 3) & 7, wx = w & 7;
    int lt = l >> 6, ly = (l >> 3) & 7, lx = l & 7;
    size_t n = (size_t)(wt * 2 + lt) * 4096 + (size_t)(wy * 8 + ly) * 64 + (wx * 8 + lx);
    const float4* s = (const float4*)(x + n * 512 + c);
    float4 a = s[0], b = s[1];
    uint4 o;
    o.x = pack2(a.x, a.y); o.y = pack2(a.z, a.w);
    o.z = pack2(b.x, b.y); o.w = pack2(b.z, b.w);
    *(uint4*)(xbf + (size_t)r * 512 + c) = o;
}

// ---------------- kernel 1: weights fp32 -> bf16, all 4 in one launch ----------------
__global__ __launch_bounds__(256) void cvt_w4(const float* __restrict__ Wq,
                                              const float* __restrict__ Wk,
                                              const float* __restrict__ Wv,
                                              const float* __restrict__ Wo,
                                              unsigned short* __restrict__ d) {
    int b = blockIdx.x >> 7;                     // which weight
    int tid = (blockIdx.x & 127) * 256 + threadIdx.x;   // per 8 elements
    const float* s = (b == 0) ? Wq : (b == 1) ? Wk : (b == 2) ? Wv : Wo;
    const float4* sp = (const float4*)s + (size_t)tid * 2;
    float4 a = sp[0], bb = sp[1];
    uint4 o;
    o.x = pack2(a.x, a.y); o.y = pack2(a.z, a.w);
    o.z = pack2(bb.x, bb.y); o.w = pack2(bb.z, bb.w);
    ((uint4*)(d + (size_t)b * 262144))[tid] = o;
}

// ---------------- kernel 2: fused QKV projection GEMM ----------------
// flat grid 2048, decoded XCD-aware: the 4 nb-blocks of one window share an XCD.
// Each block: A tile staged once per k-iter, 3 B tiles (Wq/Wk/Wv), 96 MFMA/iter.
// LDS tiles [128][64] bf16, XOR-swizzled: chunk-of-16B stored at (c ^ (row&7)).
__global__ __launch_bounds__(256, 2) void qkv_gemm(const unsigned short* __restrict__ xbf,
                                                   const unsigned short* __restrict__ wb,
                                                   unsigned short* __restrict__ Qb,
                                                   unsigned short* __restrict__ Kb,
                                                   unsigned short* __restrict__ Vb) {
    int id = blockIdx.x;
    int xcd = id & 7, rest = id >> 3;
    int w = xcd * 64 + (rest >> 2);              // window: same XCD for all 4 nb
    int nb = rest & 3;
    const unsigned short* A = xbf + (size_t)w * 128 * 512;
    const unsigned short* B0 = wb + (size_t)nb * 128 * 512;    // + pj*262144
    __shared__ unsigned short sA[128 * 64];
    __shared__ unsigned short sB[3][128 * 64];   // total LDS = 64 KB exactly
    f32x4 acc[3][4][4] = {};
    int t = threadIdx.x, lane = t & 63, wv = t >> 6;
    int wm = wv & 1, wn = wv >> 1, quad = lane >> 4, lc = lane & 15;
    int sw = lc & 7;

    // staging geometry: slot s = t + i*256; r = (t>>3) + i*32; sc = t&7.
    // (r&7) is i-independent, so the swizzled source chunk is constant.
    int sr = t >> 3;
    int gco = ((t & 7) ^ (sr & 7)) * 8;          // global col offset (elements)

    for (int k0 = 0; k0 < 512; k0 += 64) {
        __syncthreads();
        #pragma unroll
        for (int i = 0; i < 4; i++) {
            int r = sr + i * 32;
            glds16(A + (size_t)r * 512 + k0 + gco, sA + (t + i * 256) * 8);
            #pragma unroll
            for (int pj = 0; pj < 3; pj++)
                glds16(B0 + pj * 262144 + (size_t)r * 512 + k0 + gco,
                       sB[pj] + (t + i * 256) * 8);
        }
        __syncthreads();
        #pragma unroll
        for (int ks = 0; ks < 2; ks++) {
            int ch = ((quad + ks * 4) ^ sw) * 8;
            bf16x8 af[4];
            #pragma unroll
            for (int i = 0; i < 4; i++)
                af[i] = *(const bf16x8*)(&sA[(wm * 64 + i * 16 + lc) * 64 + ch]);
            #pragma unroll
            for (int pj = 0; pj < 3; pj++)
                #pragma unroll
                for (int ni = 0; ni < 4; ni++) {
                    bf16x8 bfr = *(const bf16x8*)(&sB[pj][(wn * 64 + ni * 16 + lc) * 64 + ch]);
                    #pragma unroll
                    for (int mi = 0; mi < 4; mi++)
                        acc[pj][mi][ni] = __builtin_amdgcn_mfma_f32_16x16x32_bf16(af[mi], bfr, acc[pj][mi][ni], 0, 0, 0);
                }
        }
    }

    int c0 = nb * 128 + wn * 64;
    #pragma unroll
    for (int mi = 0; mi < 4; mi++)
        #pragma unroll
        for (int ni = 0; ni < 4; ni++)
            #pragma unroll
            for (int rg = 0; rg < 4; rg++) {
                int col = c0 + ni * 16 + lc;
                int h = col >> 6, d = col & 63;
                int l = wm * 64 + mi * 16 + quad * 4 + rg;
                Qb[(((size_t)w * 8 + h) * 128 + l) * 64 + d] = f2bf(acc[0][mi][ni][rg] * 0.125f);
                Kb[(((size_t)w * 8 + h) * 128 + l) * 64 + d] = f2bf(acc[1][mi][ni][rg]);
                Vb[(((size_t)w * 8 + h) * 64 + d) * 128 + l] = f2bf(acc[2][mi][ni][rg]);
            }
}

// ---------------- kernel 3: per-(window,head) attention ----------------
// grid (8 heads, 512 windows), 256 threads (4 waves); wave wv owns rows 32wv..32wv+31
// LDS 48KB: sV [64][128], sQ [128][64], sK [128][64]; sP [128][128] overlays sQ+sK.
// All tiles XOR-swizzled (16B chunk position ^= row&7).
__global__ __launch_bounds__(256) void attn(const unsigned short* __restrict__ Qb,
                                            const unsigned short* __restrict__ Kb,
                                            const unsigned short* __restrict__ Vb,
                                            unsigned short* __restrict__ O) {
    int h = blockIdx.x, w = blockIdx.y;
    size_t base = ((size_t)w * 8 + h) * 8192;
    const unsigned short* q = Qb + base;
    const unsigned short* k = Kb + base;
    const unsigned short* v = Vb + base;   // Vt [64][128]

    __shared__ unsigned short smem[24576];           // 49152 bytes
    unsigned short* sV = smem;                       // [64][128] swizzled
    unsigned short* sQ = smem + 8192;                // [128][64] swizzled
    unsigned short* sK = smem + 16384;               // [128][64] swizzled
    unsigned short* sP = smem + 8192;                // [128][128] overlays Q+K exactly

    int t = threadIdx.x, lane = t & 63, wv = t >> 6;
    int quad = lane >> 4, lc = lane & 15;
    int sw = lc & 7;

    #pragma unroll
    for (int i = 0; i < 4; i++) {
        int s = t + i * 256;
        int r = s >> 3;
        int cq = ((s & 7) ^ (r & 7)) * 8;            // Q/K: 8 chunks/row
        glds16(q + (size_t)r * 64 + cq, sQ + s * 8);
        glds16(k + (size_t)r * 64 + cq, sK + s * 8);
        int rv = s >> 4;
        int cv = (((s & 15) ^ (rv & 7))) * 8;        // V: 16 chunks/row, swizzle low 3 bits
        glds16(v + (size_t)rv * 128 + cv, sV + s * 8);
    }
    __syncthreads();

    // S = Q @ K^T  (Q pre-scaled by 1/8)
    f32x4 acc[2][8] = {};
    #pragma unroll
    for (int ks = 0; ks < 2; ks++) {
        int ch = ((quad + ks * 4) ^ sw) * 8;
        bf16x8 af[2];
        #pragma unroll
        for (int mi = 0; mi < 2; mi++)
            af[mi] = *(const bf16x8*)(&sQ[(wv * 32 + mi * 16 + lc) * 64 + ch]);
        #pragma unroll
        for (int ni = 0; ni < 8; ni++) {
            bf16x8 bfr = *(const bf16x8*)(&sK[(ni * 16 + lc) * 64 + ch]);
            #pragma unroll
            for (int mi = 0; mi < 2; mi++)
                acc[mi][ni] = __builtin_amdgcn_mfma_f32_16x16x32_bf16(af[mi], bfr, acc[mi][ni], 0, 0, 0);
        }
    }

    // softmax fully in registers: row (mi,rg) lives in one 16-lane quad group
    #pragma unroll
    for (int mi = 0; mi < 2; mi++)
        #pragma unroll
        for (int rg = 0; rg < 4; rg++) {
            float m = -1e30f;
            #pragma unroll
            for (int ni = 0; ni < 8; ni++) m = fmaxf(m, acc[mi][ni][rg]);
            #pragma unroll
            for (int off = 1; off < 16; off <<= 1) m = fmaxf(m, __shfl_xor(m, off, 64));
            float s = 0.f;
            #pragma unroll
            for (int ni = 0; ni < 8; ni++) {
                float e = __expf(acc[mi][ni][rg] - m);
                acc[mi][ni][rg] = e;
                s += e;
            }
            #pragma unroll
            for (int off = 1; off < 16; off <<= 1) s += __shfl_xor(s, off, 64);
            float inv = 1.0f / s;
            #pragma unroll
            for (int ni = 0; ni < 8; ni++) acc[mi][ni][rg] *= inv;
        }

    __syncthreads();   // all waves done reading sQ/sK before P overlays them
    #pragma unroll
    for (int mi = 0; mi < 2; mi++)
        #pragma unroll
        for (int ni = 0; ni < 8; ni++)
            #pragma unroll
            for (int rg = 0; rg < 4; rg++) {
                int r = wv * 32 + mi * 16 + quad * 4 + rg;
                int c = ni * 16 + lc;
                sP[r * 128 + (((c >> 3) ^ (r & 7)) << 3) + (c & 7)] = f2bf(acc[mi][ni][rg]);
            }
    __syncthreads();

    // O = P @ V   (Vt as [d][k] NT operand)
    f32x4 oc[2][4] = {};
    #pragma unroll
    for (int ks = 0; ks < 4; ks++) {
        int ch = ((quad + ks * 4) ^ sw) * 8;         // 16 chunks, swizzle low 3 bits
        bf16x8 af[2];
        #pragma unroll
        for (int mi = 0; mi < 2; mi++)
            af[mi] = *(const bf16x8*)(&sP[(wv * 32 + mi * 16 + lc) * 128 + ch]);
        #pragma unroll
        for (int ni = 0; ni < 4; ni++) {
            bf16x8 bfr = *(const bf16x8*)(&sV[(ni * 16 + lc) * 128 + ch]);
            #pragma unroll
            for (int mi = 0; mi < 2; mi++)
                oc[mi][ni] = __builtin_amdgcn_mfma_f32_16x16x32_bf16(af[mi], bfr, oc[mi][ni], 0, 0, 0);
        }
    }

    #pragma unroll
    for (int mi = 0; mi < 2; mi++)
        #pragma unroll
        for (int ni = 0; ni < 4; ni++)
            #pragma unroll
            for (int rg = 0; rg < 4; rg++) {
                int l = wv * 32 + mi * 16 + quad * 4 + rg;
                int d = ni * 16 + lc;
                O[((size_t)w * 128 + l) * 512 + h * 64 + d] = f2bf(oc[mi][ni][rg]);
            }
}

// ---------------- kernel 4: output projection + bias + window merge ----------------
// flat grid 2048, XCD-aware decode: 4 nb-blocks of one rb share an XCD.
__global__ __launch_bounds__(256) void oproj_gemm(const unsigned short* __restrict__ A,
                                                  const unsigned short* __restrict__ Bw,
                                                  const float* __restrict__ bo,
                                                  float* __restrict__ out) {
    int id = blockIdx.x;
    int xcd = id & 7, rest = id >> 3;
    int rb = xcd * 64 + (rest >> 2);
    int nb = rest & 3;
    const unsigned short* Ab = A + (size_t)rb * 128 * 512;
    const unsigned short* Bb = Bw + (size_t)nb * 128 * 512;
    __shared__ unsigned short sA[128 * 64];
    __shared__ unsigned short sB[128 * 64];
    f32x4 acc[4][4] = {};
    int t = threadIdx.x, lane = t & 63, wv = t >> 6;
    int wm = wv & 1, wn = wv >> 1, quad = lane >> 4, lc = lane & 15;
    int sw = lc & 7;

    int sr = t >> 3;
    int gco = ((t & 7) ^ (sr & 7)) * 8;

    for (int k0 = 0; k0 < 512; k0 += 64) {
        __syncthreads();
        #pragma unroll
        for (int i = 0; i < 4; i++) {
            int r = sr + i * 32;
            glds16(Ab + (size_t)r * 512 + k0 + gco, sA + (t + i * 256) * 8);
            glds16(Bb + (size_t)r * 512 + k0 + gco, sB + (t + i * 256) * 8);
        }
        __syncthreads();
        #pragma unroll
        for (int ks = 0; ks < 2; ks++) {
            int ch = ((quad + ks * 4) ^ sw) * 8;
            bf16x8 af[4], bfr[4];
            #pragma unroll
            for (int i = 0; i < 4; i++) {
                af[i]  = *(const bf16x8*)(&sA[(wm * 64 + i * 16 + lc) * 64 + ch]);
                bfr[i] = *(const bf16x8*)(&sB[(wn * 64 + i * 16 + lc) * 64 + ch]);
            }
            #pragma unroll
            for (int mi = 0; mi < 4; mi++)
                #pragma unroll
                for (int ni = 0; ni < 4; ni++)
                    acc[mi][ni] = __builtin_amdgcn_mfma_f32_16x16x32_bf16(af[mi], bfr[ni], acc[mi][ni], 0, 0, 0);
        }
    }

    float bias[4];
    #pragma unroll
    for (int ni = 0; ni < 4; ni++)
        bias[ni] = bo[nb * 128 + wn * 64 + ni * 16 + lc];

    #pragma unroll
    for (int mi = 0; mi < 4; mi++)
        #pragma unroll
        for (int rg = 0; rg < 4; rg++) {
            int r = rb * 128 + wm * 64 + mi * 16 + quad * 4 + rg;
            int w = r >> 7, l = r & 127;
            int wt = w >> 6, wy = (w >> 3) & 7, wx = w & 7;
            int lt = l >> 6, ly = (l >> 3) & 7, lx = l & 7;
            size_t n = (size_t)(wt * 2 + lt) * 4096 + (size_t)(wy * 8 + ly) * 64 + (wx * 8 + lx);
            #pragma unroll
            for (int ni = 0; ni < 4; ni++) {
                int col = nb * 128 + wn * 64 + ni * 16 + lc;
                out[n * 512 + col] = acc[mi][ni][rg] + bias[ni];
            }
        }
}

extern "C" void kernel_launch(void* const* d_in, const int* in_sizes, int n_in,
                              void* d_out, int out_size, void* d_ws, size_t ws_size,
                              hipStream_t stream) {
    const float* x  = (const float*)d_in[0];
    const float* Wq = (const float*)d_in[1];
    const float* Wk = (const float*)d_in[2];
    const float* Wv = (const float*)d_in[3];
    const float* Wo = (const float*)d_in[4];
    const float* bo = (const float*)d_in[5];
    float* out = (float*)d_out;

    char* ws = (char*)d_ws;
    unsigned short* xbf = (unsigned short*)(ws);                  // also O after attention
    unsigned short* Qb  = (unsigned short*)(ws + 67108864);
    unsigned short* Kb  = (unsigned short*)(ws + 134217728);
    unsigned short* Vb  = (unsigned short*)(ws + 201326592);
    unsigned short* Wqb = (unsigned short*)(ws + 268435456);      // Wq,Wk,Wv,Wo consecutive

    gather_cvt<<<16384, 256, 0, stream>>>(x, xbf);
    cvt_w4<<<512, 256, 0, stream>>>(Wq, Wk, Wv, Wo, Wqb);

    qkv_gemm<<<2048, 256, 0, stream>>>(xbf, Wqb, Qb, Kb, Vb);
    attn<<<dim3(8, 512), 256, 0, stream>>>(Qb, Kb, Vb, xbf);
    oproj_gemm<<<2048, 256, 0, stream>>>(xbf, Wqb + 786432, bo, out);
}